// Round 4
// baseline (876.574 us; speedup 1.0000x reference)
//
#include <hip/hip_runtime.h>
#include <hip/hip_bf16.h>
#include <cstdint>

#define T_TOK 8192
#define DM 1024
#define NE 8
#define DFF 4096

#define BM 256
#define BN 256
#define BK 64

typedef __attribute__((ext_vector_type(8))) short bf16x8;
typedef __attribute__((ext_vector_type(4))) float f32x4;

__device__ __forceinline__ unsigned short f2bf(float f) {
  unsigned int b = __float_as_uint(f);
  b += 0x7FFFu + ((b >> 16) & 1u);
  return (unsigned short)(b >> 16);
}

__device__ __forceinline__ float gelu_exact(float v) {
  return 0.5f * v * (1.0f + erff(v * 0.70710678118654752440f));
}

// ---- generic fp32 -> bf16, 8 elems/thread ----
__global__ void cvt_kernel(const float* __restrict__ x, unsigned short* __restrict__ xb) {
  size_t i = (size_t)blockIdx.x * blockDim.x + threadIdx.x;
  const f32x4* p = (const f32x4*)x;
  f32x4 a = p[2 * i];
  f32x4 b = p[2 * i + 1];
  union { bf16x8 v; unsigned short u[8]; } o;
  o.u[0] = f2bf(a.x); o.u[1] = f2bf(a.y); o.u[2] = f2bf(a.z); o.u[3] = f2bf(a.w);
  o.u[4] = f2bf(b.x); o.u[5] = f2bf(b.y); o.u[6] = f2bf(b.z); o.u[7] = f2bf(b.w);
  ((bf16x8*)xb)[i] = o.v;
}

// ---- router: one wave per token, fp32 exact ----
__global__ void router_kernel(const float* __restrict__ x, const float* __restrict__ rw,
                              const float* __restrict__ rb, int* __restrict__ counts,
                              int* __restrict__ tlist, float* __restrict__ wlist) {
  const int lane = threadIdx.x & 63;
  const int t = blockIdx.x * 4 + (threadIdx.x >> 6);
  const float* xr = x + (size_t)t * DM;
  float acc[NE];
#pragma unroll
  for (int e = 0; e < NE; ++e) acc[e] = 0.0f;
#pragma unroll
  for (int i = 0; i < 16; ++i) {
    int d = lane + i * 64;
    float xv = xr[d];
    const float* wr = rw + (size_t)d * NE;
#pragma unroll
    for (int e = 0; e < NE; ++e) acc[e] = fmaf(xv, wr[e], acc[e]);
  }
#pragma unroll
  for (int off = 32; off; off >>= 1) {
#pragma unroll
    for (int e = 0; e < NE; ++e) acc[e] += __shfl_xor(acc[e], off);
  }
  float m = -1e30f;
#pragma unroll
  for (int e = 0; e < NE; ++e) { acc[e] += rb[e]; m = fmaxf(m, acc[e]); }
  float p[NE]; float s = 0.0f;
#pragma unroll
  for (int e = 0; e < NE; ++e) { p[e] = expf(acc[e] - m); s += p[e]; }
  int e1 = 0; float p1 = p[0];
#pragma unroll
  for (int e = 1; e < NE; ++e) if (p[e] > p1) { p1 = p[e]; e1 = e; }
  int e2 = -1; float p2 = -1e30f;
#pragma unroll
  for (int e = 0; e < NE; ++e) if (e != e1 && p[e] > p2) { p2 = p[e]; e2 = e; }
  float inv = 1.0f / s;
  if (lane == 0) {
    int r1 = atomicAdd(counts + e1, 1);
    tlist[e1 * T_TOK + r1] = t; wlist[e1 * T_TOK + r1] = p1 * inv;
    int r2 = atomicAdd(counts + e2, 1);
    tlist[e2 * T_TOK + r2] = t; wlist[e2 * T_TOK + r2] = p2 * inv;
  }
}

__global__ void prefix_kernel(const int* __restrict__ counts, int* __restrict__ offs) {
  int s = 0;
  for (int e = 0; e < NE; ++e) { offs[e] = s; s += counts[e]; }
}

#define GL2LDS16(g, l) \
  __builtin_amdgcn_global_load_lds((const __attribute__((address_space(1))) unsigned int*)(g), \
                                   (__attribute__((address_space(3))) unsigned int*)(l), 16, 0, 0)

// schedule helpers (raw barrier + hand waits; compiler memory fences around)
#define VMCNT(n) asm volatile("s_waitcnt vmcnt(" #n ")" ::: "memory")
#define LGKM0    asm volatile("s_waitcnt lgkmcnt(0)" ::: "memory")
#define BARRIER() do { asm volatile("" ::: "memory"); __builtin_amdgcn_s_barrier(); asm volatile("" ::: "memory"); } while (0)

// staging: 8 gl2lds per K-step (4 A-issues + 4 B-issues), 64 rows x 8 slots each
#define STAGE(bufi, t) do { \
  const int koff_ = (t) * BK; \
  _Pragma("unroll") \
  for (int i_ = 0; i_ < 4; ++i_) { \
    GL2LDS16(asrc[i_] + koff_, &sA[bufi][i_ * 4096 + tid * 8]); \
    GL2LDS16(bsrc[i_] + koff_, &sB[bufi][i_ * 4096 + tid * 8]); \
  } \
} while (0)

// per-wave compute of one BK=64 tile: 24 swizzled ds_read_b128 + 64 MFMA
#define COMPUTE(b) do { \
  _Pragma("unroll") \
  for (int ks_ = 0; ks_ < 2; ++ks_) { \
    bf16x8 af_[8], bf_[4]; \
    _Pragma("unroll") \
    for (int m_ = 0; m_ < 8; ++m_) { \
      const int row_ = wr + m_ * 16 + lr; \
      const int slot_ = (ks_ * 4 + g) ^ (lr & 7); \
      af_[m_] = *(const bf16x8*)&sA[b][row_ * 64 + slot_ * 8]; \
    } \
    _Pragma("unroll") \
    for (int n_ = 0; n_ < 4; ++n_) { \
      const int row_ = wc + n_ * 16 + lr; \
      const int slot_ = (ks_ * 4 + g) ^ (lr & 7); \
      bf_[n_] = *(const bf16x8*)&sB[b][row_ * 64 + slot_ * 8]; \
    } \
    _Pragma("unroll") \
    for (int m_ = 0; m_ < 8; ++m_) \
      _Pragma("unroll") \
      for (int n_ = 0; n_ < 4; ++n_) \
        acc[m_][n_] = __builtin_amdgcn_mfma_f32_16x16x32_bf16(af_[m_], bf_[n_], acc[m_][n_], 0, 0, 0); \
  } \
} while (0)

// ---- GEMM1: h = gelu(x[tok] @ up[e]^T), 256x256 tile, counted-vmcnt 2-phase ----
__global__ __launch_bounds__(512, 2) void gemm_up_kernel(
    const unsigned short* __restrict__ xb, const unsigned short* __restrict__ wb,
    const int* __restrict__ counts, const int* __restrict__ offs,
    const int* __restrict__ tlist, unsigned short* __restrict__ h) {
  const int e = blockIdx.z;
  const int cnt = counts[e];
  const int rt = blockIdx.y;
  if (rt * BM >= cnt) return;
  const int ct = blockIdx.x;

  __shared__ unsigned short sA[2][BM * BK];
  __shared__ unsigned short sB[2][BN * BK];

  const int tid = threadIdx.x;
  const int wid = tid >> 6, ln = tid & 63;
  const int srow = tid >> 3;                 // staging row within 64-row group
  const int swz  = (tid & 7) ^ (srow & 7);   // inverse-swizzled source 16B-slot

  // A sources: gathered token rows, clamped for partial tiles
  const unsigned short* asrc[4];
#pragma unroll
  for (int i = 0; i < 4; ++i) {
    int r = rt * BM + i * 64 + srow;
    int tok = tlist[e * T_TOK + (r < cnt ? r : cnt - 1)];
    asrc[i] = xb + (size_t)tok * DM + swz * 8;
  }
  // B sources: up weights [E][DFF][DM]
  const unsigned short* bsrc[4];
#pragma unroll
  for (int i = 0; i < 4; ++i)
    bsrc[i] = wb + (size_t)e * DFF * DM + (size_t)(ct * BN + i * 64 + srow) * DM + swz * 8;

  const int wr = (wid >> 2) * 128, wc = (wid & 3) * 64;
  const int lr = ln & 15, g = ln >> 4;

  f32x4 acc[8][4] = {};

  const int nt = DM / BK;   // 16
  int buf = 0;
  STAGE(0, 0);
  for (int t = 0; t < nt - 1; ++t) {
    STAGE(buf ^ 1, t + 1);
    VMCNT(8);
    BARRIER();
    COMPUTE(buf);
    LGKM0;
    BARRIER();
    buf ^= 1;
  }
  VMCNT(0);
  BARRIER();
  COMPUTE(buf);

  const size_t hbase = (size_t)offs[e];
#pragma unroll
  for (int m = 0; m < 8; ++m) {
    int rloc = wr + m * 16 + g * 4;
#pragma unroll
    for (int j = 0; j < 4; ++j) {
      int row = rt * BM + rloc + j;
      if (row < cnt) {
        unsigned short* hp = h + (hbase + row) * (size_t)DFF + ct * BN + wc + lr;
#pragma unroll
        for (int n = 0; n < 4; ++n) hp[n * 16] = f2bf(gelu_exact(acc[m][n][j]));
      }
    }
  }
}

// ---- GEMM2: out[tok] += w * (h @ down[e]^T), 256x256 tile, atomic scatter ----
__global__ __launch_bounds__(512, 2) void gemm_down_kernel(
    const unsigned short* __restrict__ h, const unsigned short* __restrict__ wb,
    const int* __restrict__ counts, const int* __restrict__ offs,
    const int* __restrict__ tlist, const float* __restrict__ wlist,
    float* __restrict__ out) {
  const int e = blockIdx.z;
  const int cnt = counts[e];
  const int rt = blockIdx.y;
  if (rt * BM >= cnt) return;
  const int ct = blockIdx.x;

  __shared__ unsigned short sA[2][BM * BK];
  __shared__ unsigned short sB[2][BN * BK];

  const int tid = threadIdx.x;
  const int wid = tid >> 6, ln = tid & 63;
  const int srow = tid >> 3;
  const int swz  = (tid & 7) ^ (srow & 7);
  const size_t hbase = (size_t)offs[e];

  // A sources: compacted h rows, clamped
  const unsigned short* asrc[4];
#pragma unroll
  for (int i = 0; i < 4; ++i) {
    int r = rt * BM + i * 64 + srow;
    size_t hrow = hbase + (size_t)(r < cnt ? r : cnt - 1);
    asrc[i] = h + hrow * DFF + swz * 8;
  }
  // B sources: down weights [E][DM][DFF]
  const unsigned short* bsrc[4];
#pragma unroll
  for (int i = 0; i < 4; ++i)
    bsrc[i] = wb + (size_t)e * DM * DFF + (size_t)(ct * BN + i * 64 + srow) * DFF + swz * 8;

  const int wr = (wid >> 2) * 128, wc = (wid & 3) * 64;
  const int lr = ln & 15, g = ln >> 4;

  f32x4 acc[8][4] = {};

  const int nt = DFF / BK;  // 64
  int buf = 0;
  STAGE(0, 0);
  for (int t = 0; t < nt - 1; ++t) {
    STAGE(buf ^ 1, t + 1);
    VMCNT(8);
    BARRIER();
    COMPUTE(buf);
    LGKM0;
    BARRIER();
    buf ^= 1;
  }
  VMCNT(0);
  BARRIER();
  COMPUTE(buf);

#pragma unroll
  for (int m = 0; m < 8; ++m) {
    int rloc = wr + m * 16 + g * 4;
#pragma unroll
    for (int j = 0; j < 4; ++j) {
      int row = rt * BM + rloc + j;
      if (row < cnt) {
        int tok = tlist[e * T_TOK + row];
        float w = wlist[e * T_TOK + row];
        float* op = out + (size_t)tok * DM + ct * BN + wc + lr;
#pragma unroll
        for (int n = 0; n < 4; ++n) atomicAdd(op + n * 16, w * acc[m][n][j]);
      }
    }
  }
}

extern "C" void kernel_launch(void* const* d_in, const int* in_sizes, int n_in,
                              void* d_out, int out_size, void* d_ws, size_t ws_size,
                              hipStream_t stream) {
  const float* x  = (const float*)d_in[0];
  const float* rw = (const float*)d_in[1];
  const float* rb = (const float*)d_in[2];
  const float* up = (const float*)d_in[3];
  const float* dn = (const float*)d_in[4];
  float* out = (float*)d_out;
  char* ws = (char*)d_ws;

  int*   counts = (int*)(ws + 0);                          // 8 ints
  int*   offs   = (int*)(ws + 128);                        // 8 ints
  int*   tlist  = (int*)(ws + 1024);                       // 256 KB
  float* wlist  = (float*)(ws + 1024 + 262144);            // 256 KB
  unsigned short* xb = (unsigned short*)(ws + 525312);     // 16 MB  (8192x1024 bf16)
  unsigned short* h  = (unsigned short*)(ws + 17302528);   // 128 MB (16384x4096 bf16)
  unsigned short* wbuf = (unsigned short*)(ws + 151520256);// 64 MB  (8x4096x1024 bf16, reused)

  hipMemsetAsync(counts, 0, 64, stream);
  hipMemsetAsync(d_out, 0, (size_t)T_TOK * DM * sizeof(float), stream);

  cvt_kernel<<<dim3((T_TOK * DM / 8) / 256), 256, 0, stream>>>(x, xb);
  router_kernel<<<dim3(T_TOK / 4), 256, 0, stream>>>(x, rw, rb, counts, tlist, wlist);
  prefix_kernel<<<dim3(1), 1, 0, stream>>>(counts, offs);

  // up weights -> bf16, then GEMM1 (grid: 16 x 32 x 8; inactive row-tiles exit)
  cvt_kernel<<<dim3((NE * DFF * DM / 8) / 256), 256, 0, stream>>>(up, wbuf);
  gemm_up_kernel<<<dim3(DFF / BN, T_TOK / BM, NE), 512, 0, stream>>>(xb, wbuf, counts, offs, tlist, h);

  // down weights -> bf16 (reuse buffer), then GEMM2 (grid: 4 x 32 x 8)
  cvt_kernel<<<dim3((NE * DM * DFF / 8) / 256), 256, 0, stream>>>(dn, wbuf);
  gemm_down_kernel<<<dim3(DM / BN, T_TOK / BM, NE), 512, 0, stream>>>(h, wbuf, counts, offs, tlist, wlist, out);
}

// Round 5
// 857.665 us; speedup vs baseline: 1.0220x; 1.0220x over previous
//
#include <hip/hip_runtime.h>
#include <hip/hip_bf16.h>
#include <cstdint>

#define T_TOK 8192
#define DM 1024
#define NE 8
#define DFF 4096

#define BM 256
#define BN 256
#define BK 64
#define MAXRT 72   // worst-case sum over experts of ceil(cnt_e/BM)

typedef __attribute__((ext_vector_type(8))) short bf16x8;
typedef __attribute__((ext_vector_type(4))) float f32x4;

__device__ __forceinline__ unsigned short f2bf(float f) {
  unsigned int b = __float_as_uint(f);
  b += 0x7FFFu + ((b >> 16) & 1u);
  return (unsigned short)(b >> 16);
}

__device__ __forceinline__ float gelu_exact(float v) {
  return 0.5f * v * (1.0f + erff(v * 0.70710678118654752440f));
}

// ---- generic fp32 -> bf16, 8 elems/thread ----
__global__ void cvt_kernel(const float* __restrict__ x, unsigned short* __restrict__ xb) {
  size_t i = (size_t)blockIdx.x * blockDim.x + threadIdx.x;
  const f32x4* p = (const f32x4*)x;
  f32x4 a = p[2 * i];
  f32x4 b = p[2 * i + 1];
  union { bf16x8 v; unsigned short u[8]; } o;
  o.u[0] = f2bf(a.x); o.u[1] = f2bf(a.y); o.u[2] = f2bf(a.z); o.u[3] = f2bf(a.w);
  o.u[4] = f2bf(b.x); o.u[5] = f2bf(b.y); o.u[6] = f2bf(b.z); o.u[7] = f2bf(b.w);
  ((bf16x8*)xb)[i] = o.v;
}

// ---- router: one wave per token, fp32 exact ----
__global__ void router_kernel(const float* __restrict__ x, const float* __restrict__ rw,
                              const float* __restrict__ rb, int* __restrict__ counts,
                              int* __restrict__ tlist, float* __restrict__ wlist) {
  const int lane = threadIdx.x & 63;
  const int t = blockIdx.x * 4 + (threadIdx.x >> 6);
  const float* xr = x + (size_t)t * DM;
  float acc[NE];
#pragma unroll
  for (int e = 0; e < NE; ++e) acc[e] = 0.0f;
#pragma unroll
  for (int i = 0; i < 16; ++i) {
    int d = lane + i * 64;
    float xv = xr[d];
    const float* wr = rw + (size_t)d * NE;
#pragma unroll
    for (int e = 0; e < NE; ++e) acc[e] = fmaf(xv, wr[e], acc[e]);
  }
#pragma unroll
  for (int off = 32; off; off >>= 1) {
#pragma unroll
    for (int e = 0; e < NE; ++e) acc[e] += __shfl_xor(acc[e], off);
  }
  float m = -1e30f;
#pragma unroll
  for (int e = 0; e < NE; ++e) { acc[e] += rb[e]; m = fmaxf(m, acc[e]); }
  float p[NE]; float s = 0.0f;
#pragma unroll
  for (int e = 0; e < NE; ++e) { p[e] = expf(acc[e] - m); s += p[e]; }
  int e1 = 0; float p1 = p[0];
#pragma unroll
  for (int e = 1; e < NE; ++e) if (p[e] > p1) { p1 = p[e]; e1 = e; }
  int e2 = -1; float p2 = -1e30f;
#pragma unroll
  for (int e = 0; e < NE; ++e) if (e != e1 && p[e] > p2) { p2 = p[e]; e2 = e; }
  float inv = 1.0f / s;
  if (lane == 0) {
    int r1 = atomicAdd(counts + e1, 1);
    tlist[e1 * T_TOK + r1] = t; wlist[e1 * T_TOK + r1] = p1 * inv;
    int r2 = atomicAdd(counts + e2, 1);
    tlist[e2 * T_TOK + r2] = t; wlist[e2 * T_TOK + r2] = p2 * inv;
  }
}

// ---- prefix + active row-tile map ----
__global__ void prefix_kernel(const int* __restrict__ counts, int* __restrict__ offs,
                              int* __restrict__ rowmap, int* __restrict__ nrt) {
  int s = 0, n = 0;
  for (int e = 0; e < NE; ++e) {
    offs[e] = s; s += counts[e];
    int ntile = (counts[e] + BM - 1) / BM;
    for (int r = 0; r < ntile; ++r) rowmap[n++] = (e << 16) | r;
  }
  nrt[0] = n;
}

#define GL2LDS16(g, l) \
  __builtin_amdgcn_global_load_lds((const __attribute__((address_space(1))) unsigned int*)(g), \
                                   (__attribute__((address_space(3))) unsigned int*)(l), 16, 0, 0)

#define VMCNT0   asm volatile("s_waitcnt vmcnt(0)" ::: "memory")
#define BARRIER() do { asm volatile("" ::: "memory"); __builtin_amdgcn_s_barrier(); asm volatile("" ::: "memory"); } while (0)

// staging: 8 gl2lds per K-step (4 A + 4 B)
#define STAGE(bufi, t) do { \
  const int koff_ = (t) * BK; \
  _Pragma("unroll") \
  for (int i_ = 0; i_ < 4; ++i_) { \
    GL2LDS16(asrc[i_] + koff_, &sA[bufi][i_ * 4096 + tid * 8]); \
    GL2LDS16(bsrc[i_] + koff_, &sB[bufi][i_ * 4096 + tid * 8]); \
  } \
} while (0)

// per-wave compute of one BK=64 tile: 24 swizzled ds_read_b128 + 64 MFMA
#define COMPUTE(b) do { \
  _Pragma("unroll") \
  for (int ks_ = 0; ks_ < 2; ++ks_) { \
    bf16x8 af_[8], bf_[4]; \
    _Pragma("unroll") \
    for (int m_ = 0; m_ < 8; ++m_) { \
      const int row_ = wr + m_ * 16 + lr; \
      const int slot_ = (ks_ * 4 + g) ^ (lr & 7); \
      af_[m_] = *(const bf16x8*)&sA[b][row_ * 64 + slot_ * 8]; \
    } \
    _Pragma("unroll") \
    for (int n_ = 0; n_ < 4; ++n_) { \
      const int row_ = wc + n_ * 16 + lr; \
      const int slot_ = (ks_ * 4 + g) ^ (lr & 7); \
      bf_[n_] = *(const bf16x8*)&sB[b][row_ * 64 + slot_ * 8]; \
    } \
    _Pragma("unroll") \
    for (int m_ = 0; m_ < 8; ++m_) \
      _Pragma("unroll") \
      for (int n_ = 0; n_ < 4; ++n_) \
        acc[m_][n_] = __builtin_amdgcn_mfma_f32_16x16x32_bf16(af_[m_], bf_[n_], acc[m_][n_], 0, 0, 0); \
  } \
} while (0)

// ---- GEMM1: h = gelu(x[tok] @ up[e]^T), T3-minimum 2-phase ----
__global__ __launch_bounds__(512, 2) void gemm_up_kernel(
    const unsigned short* __restrict__ xb, const unsigned short* __restrict__ wb,
    const int* __restrict__ counts, const int* __restrict__ offs,
    const int* __restrict__ rowmap, const int* __restrict__ nrt,
    const int* __restrict__ tlist, unsigned short* __restrict__ h) {
  if ((int)blockIdx.y >= nrt[0]) return;
  const int item = rowmap[blockIdx.y];
  const int e = item >> 16, rt = item & 0xFFFF;
  const int cnt = counts[e];
  const int ct = blockIdx.x;

  __shared__ unsigned short sA[2][BM * BK];
  __shared__ unsigned short sB[2][BN * BK];

  const int tid = threadIdx.x;
  const int wid = tid >> 6, ln = tid & 63;
  const int srow = tid >> 3;
  const int swz  = (tid & 7) ^ (srow & 7);

  const unsigned short* asrc[4];
#pragma unroll
  for (int i = 0; i < 4; ++i) {
    int r = rt * BM + i * 64 + srow;
    int tok = tlist[e * T_TOK + (r < cnt ? r : cnt - 1)];
    asrc[i] = xb + (size_t)tok * DM + swz * 8;
  }
  const unsigned short* bsrc[4];
#pragma unroll
  for (int i = 0; i < 4; ++i)
    bsrc[i] = wb + (size_t)e * DFF * DM + (size_t)(ct * BN + i * 64 + srow) * DM + swz * 8;

  const int wr = (wid >> 2) * 128, wc = (wid & 3) * 64;
  const int lr = ln & 15, g = ln >> 4;

  f32x4 acc[8][4] = {};

  const int nt = DM / BK;   // 16
  int buf = 0;
  STAGE(0, 0);
  VMCNT0;
  BARRIER();
  for (int t = 0; t < nt; ++t) {
    if (t + 1 < nt) STAGE(buf ^ 1, t + 1);
    COMPUTE(buf);
    VMCNT0;
    BARRIER();
    buf ^= 1;
  }

  const size_t hbase = (size_t)offs[e];
#pragma unroll
  for (int m = 0; m < 8; ++m) {
    int rloc = wr + m * 16 + g * 4;
#pragma unroll
    for (int j = 0; j < 4; ++j) {
      int row = rt * BM + rloc + j;
      if (row < cnt) {
        unsigned short* hp = h + (hbase + row) * (size_t)DFF + ct * BN + wc + lr;
#pragma unroll
        for (int n = 0; n < 4; ++n) hp[n * 16] = f2bf(gelu_exact(acc[m][n][j]));
      }
    }
  }
}

// ---- GEMM2: out[tok] += w * (h @ down[e]^T), T3-minimum 2-phase ----
__global__ __launch_bounds__(512, 2) void gemm_down_kernel(
    const unsigned short* __restrict__ h, const unsigned short* __restrict__ wb,
    const int* __restrict__ counts, const int* __restrict__ offs,
    const int* __restrict__ rowmap, const int* __restrict__ nrt,
    const int* __restrict__ tlist, const float* __restrict__ wlist,
    float* __restrict__ out) {
  if ((int)blockIdx.y >= nrt[0]) return;
  const int item = rowmap[blockIdx.y];
  const int e = item >> 16, rt = item & 0xFFFF;
  const int cnt = counts[e];
  const int ct = blockIdx.x;

  __shared__ unsigned short sA[2][BM * BK];
  __shared__ unsigned short sB[2][BN * BK];

  const int tid = threadIdx.x;
  const int wid = tid >> 6, ln = tid & 63;
  const int srow = tid >> 3;
  const int swz  = (tid & 7) ^ (srow & 7);
  const size_t hbase = (size_t)offs[e];

  const unsigned short* asrc[4];
#pragma unroll
  for (int i = 0; i < 4; ++i) {
    int r = rt * BM + i * 64 + srow;
    size_t hrow = hbase + (size_t)(r < cnt ? r : cnt - 1);
    asrc[i] = h + hrow * DFF + swz * 8;
  }
  const unsigned short* bsrc[4];
#pragma unroll
  for (int i = 0; i < 4; ++i)
    bsrc[i] = wb + (size_t)e * DM * DFF + (size_t)(ct * BN + i * 64 + srow) * DFF + swz * 8;

  const int wr = (wid >> 2) * 128, wc = (wid & 3) * 64;
  const int lr = ln & 15, g = ln >> 4;

  f32x4 acc[8][4] = {};

  const int nt = DFF / BK;  // 64
  int buf = 0;
  STAGE(0, 0);
  VMCNT0;
  BARRIER();
  for (int t = 0; t < nt; ++t) {
    if (t + 1 < nt) STAGE(buf ^ 1, t + 1);
    COMPUTE(buf);
    VMCNT0;
    BARRIER();
    buf ^= 1;
  }

#pragma unroll
  for (int m = 0; m < 8; ++m) {
    int rloc = wr + m * 16 + g * 4;
#pragma unroll
    for (int j = 0; j < 4; ++j) {
      int row = rt * BM + rloc + j;
      if (row < cnt) {
        int tok = tlist[e * T_TOK + row];
        float w = wlist[e * T_TOK + row];
        float* op = out + (size_t)tok * DM + ct * BN + wc + lr;
#pragma unroll
        for (int n = 0; n < 4; ++n) atomicAdd(op + n * 16, w * acc[m][n][j]);
      }
    }
  }
}

extern "C" void kernel_launch(void* const* d_in, const int* in_sizes, int n_in,
                              void* d_out, int out_size, void* d_ws, size_t ws_size,
                              hipStream_t stream) {
  const float* x  = (const float*)d_in[0];
  const float* rw = (const float*)d_in[1];
  const float* rb = (const float*)d_in[2];
  const float* up = (const float*)d_in[3];
  const float* dn = (const float*)d_in[4];
  float* out = (float*)d_out;
  char* ws = (char*)d_ws;

  int*   counts = (int*)(ws + 0);                          // 8 ints
  int*   offs   = (int*)(ws + 128);                        // 8 ints
  int*   nrt    = (int*)(ws + 256);                        // 1 int
  int*   rowmap = (int*)(ws + 512);                        // 72 ints
  int*   tlist  = (int*)(ws + 1024);                       // 256 KB
  float* wlist  = (float*)(ws + 1024 + 262144);            // 256 KB
  unsigned short* xb = (unsigned short*)(ws + 525312);     // 16 MB  (8192x1024 bf16)
  unsigned short* h  = (unsigned short*)(ws + 17302528);   // 128 MB (16384x4096 bf16)
  unsigned short* wbuf = (unsigned short*)(ws + 151520256);// 64 MB  (8x4096x1024 bf16, reused)

  hipMemsetAsync(counts, 0, 64, stream);
  hipMemsetAsync(d_out, 0, (size_t)T_TOK * DM * sizeof(float), stream);

  cvt_kernel<<<dim3((T_TOK * DM / 8) / 256), 256, 0, stream>>>(x, xb);
  router_kernel<<<dim3(T_TOK / 4), 256, 0, stream>>>(x, rw, rb, counts, tlist, wlist);
  prefix_kernel<<<dim3(1), 1, 0, stream>>>(counts, offs, rowmap, nrt);

  // up weights -> bf16, then GEMM1 (grid: 16 x 72-active)
  cvt_kernel<<<dim3((NE * DFF * DM / 8) / 256), 256, 0, stream>>>(up, wbuf);
  gemm_up_kernel<<<dim3(DFF / BN, MAXRT), 512, 0, stream>>>(xb, wbuf, counts, offs, rowmap, nrt, tlist, h);

  // down weights -> bf16 (reuse buffer), then GEMM2 (grid: 4 x 72-active)
  cvt_kernel<<<dim3((NE * DM * DFF / 8) / 256), 256, 0, stream>>>(dn, wbuf);
  gemm_down_kernel<<<dim3(DM / BN, MAXRT), 512, 0, stream>>>(h, wbuf, counts, offs, rowmap, nrt, tlist, wlist, out);
}

// Round 6
// 833.766 us; speedup vs baseline: 1.0513x; 1.0287x over previous
//
#include <hip/hip_runtime.h>
#include <hip/hip_bf16.h>
#include <cstdint>

#define T_TOK 8192
#define DM 1024
#define NE 8
#define DFF 4096

#define BM 256
#define BN 256
#define BK 64
#define MAXRT 72   // worst-case sum over experts of ceil(cnt_e/BM); must be %8==0

typedef __attribute__((ext_vector_type(8))) short bf16x8;
typedef __attribute__((ext_vector_type(4))) float f32x4;

__device__ __forceinline__ unsigned short f2bf(float f) {
  unsigned int b = __float_as_uint(f);
  b += 0x7FFFu + ((b >> 16) & 1u);
  return (unsigned short)(b >> 16);
}

__device__ __forceinline__ float gelu_exact(float v) {
  return 0.5f * v * (1.0f + erff(v * 0.70710678118654752440f));
}

// ---- generic fp32 -> bf16, 8 elems/thread ----
__global__ void cvt_kernel(const float* __restrict__ x, unsigned short* __restrict__ xb) {
  size_t i = (size_t)blockIdx.x * blockDim.x + threadIdx.x;
  const f32x4* p = (const f32x4*)x;
  f32x4 a = p[2 * i];
  f32x4 b = p[2 * i + 1];
  union { bf16x8 v; unsigned short u[8]; } o;
  o.u[0] = f2bf(a.x); o.u[1] = f2bf(a.y); o.u[2] = f2bf(a.z); o.u[3] = f2bf(a.w);
  o.u[4] = f2bf(b.x); o.u[5] = f2bf(b.y); o.u[6] = f2bf(b.z); o.u[7] = f2bf(b.w);
  ((bf16x8*)xb)[i] = o.v;
}

// ---- router: one wave per token, fp32 exact ----
__global__ void router_kernel(const float* __restrict__ x, const float* __restrict__ rw,
                              const float* __restrict__ rb, int* __restrict__ counts,
                              int* __restrict__ tlist, float* __restrict__ wlist) {
  const int lane = threadIdx.x & 63;
  const int t = blockIdx.x * 4 + (threadIdx.x >> 6);
  const float* xr = x + (size_t)t * DM;
  float acc[NE];
#pragma unroll
  for (int e = 0; e < NE; ++e) acc[e] = 0.0f;
#pragma unroll
  for (int i = 0; i < 16; ++i) {
    int d = lane + i * 64;
    float xv = xr[d];
    const float* wr = rw + (size_t)d * NE;
#pragma unroll
    for (int e = 0; e < NE; ++e) acc[e] = fmaf(xv, wr[e], acc[e]);
  }
#pragma unroll
  for (int off = 32; off; off >>= 1) {
#pragma unroll
    for (int e = 0; e < NE; ++e) acc[e] += __shfl_xor(acc[e], off);
  }
  float m = -1e30f;
#pragma unroll
  for (int e = 0; e < NE; ++e) { acc[e] += rb[e]; m = fmaxf(m, acc[e]); }
  float p[NE]; float s = 0.0f;
#pragma unroll
  for (int e = 0; e < NE; ++e) { p[e] = expf(acc[e] - m); s += p[e]; }
  int e1 = 0; float p1 = p[0];
#pragma unroll
  for (int e = 1; e < NE; ++e) if (p[e] > p1) { p1 = p[e]; e1 = e; }
  int e2 = -1; float p2 = -1e30f;
#pragma unroll
  for (int e = 0; e < NE; ++e) if (e != e1 && p[e] > p2) { p2 = p[e]; e2 = e; }
  float inv = 1.0f / s;
  if (lane == 0) {
    int r1 = atomicAdd(counts + e1, 1);
    tlist[e1 * T_TOK + r1] = t; wlist[e1 * T_TOK + r1] = p1 * inv;
    int r2 = atomicAdd(counts + e2, 1);
    tlist[e2 * T_TOK + r2] = t; wlist[e2 * T_TOK + r2] = p2 * inv;
  }
}

// ---- prefix + active row-tile map ----
__global__ void prefix_kernel(const int* __restrict__ counts, int* __restrict__ offs,
                              int* __restrict__ rowmap, int* __restrict__ nrt) {
  int s = 0, n = 0;
  for (int e = 0; e < NE; ++e) {
    offs[e] = s; s += counts[e];
    int ntile = (counts[e] + BM - 1) / BM;
    for (int r = 0; r < ntile; ++r) rowmap[n++] = (e << 16) | r;
  }
  nrt[0] = n;
}

#define GL2LDS16(g, l) \
  __builtin_amdgcn_global_load_lds((const __attribute__((address_space(1))) unsigned int*)(g), \
                                   (__attribute__((address_space(3))) unsigned int*)(l), 16, 0, 0)

#define VMCNT8   asm volatile("s_waitcnt vmcnt(8)" ::: "memory")
#define VMCNT0   asm volatile("s_waitcnt vmcnt(0)" ::: "memory")
#define LGKM0    asm volatile("s_waitcnt lgkmcnt(0)" ::: "memory")
#define BARRIER() do { asm volatile("" ::: "memory"); __builtin_amdgcn_s_barrier(); asm volatile("" ::: "memory"); } while (0)

// staging: 8 gl2lds per K-step per wave (4 A + 4 B), 64-row groups, 16B/lane
#define STAGE(bufi, t) do { \
  const int koff_ = (t) * BK; \
  _Pragma("unroll") \
  for (int i_ = 0; i_ < 4; ++i_) { \
    GL2LDS16(asrc[i_] + koff_, &sA[bufi][i_ * 4096 + tid * 8]); \
    GL2LDS16(bsrc[i_] + koff_, &sB[bufi][i_ * 4096 + tid * 8]); \
  } \
} while (0)

// per-wave compute of one BK=64 tile: 24 swizzled ds_read_b128 + 64 MFMA
#define COMPUTE(b) do { \
  _Pragma("unroll") \
  for (int ks_ = 0; ks_ < 2; ++ks_) { \
    bf16x8 af_[8], bf_[4]; \
    _Pragma("unroll") \
    for (int m_ = 0; m_ < 8; ++m_) { \
      const int row_ = wr + m_ * 16 + lr; \
      const int slot_ = (ks_ * 4 + g) ^ (lr & 7); \
      af_[m_] = *(const bf16x8*)&sA[b][row_ * 64 + slot_ * 8]; \
    } \
    _Pragma("unroll") \
    for (int n_ = 0; n_ < 4; ++n_) { \
      const int row_ = wc + n_ * 16 + lr; \
      const int slot_ = (ks_ * 4 + g) ^ (lr & 7); \
      bf_[n_] = *(const bf16x8*)&sB[b][row_ * 64 + slot_ * 8]; \
    } \
    _Pragma("unroll") \
    for (int m_ = 0; m_ < 8; ++m_) \
      _Pragma("unroll") \
      for (int n_ = 0; n_ < 4; ++n_) \
        acc[m_][n_] = __builtin_amdgcn_mfma_f32_16x16x32_bf16(af_[m_], bf_[n_], acc[m_][n_], 0, 0, 0); \
  } \
} while (0)

// depth-2 pipelined K-loop: tile t waits only its own loads (t+1 stays in flight);
// refill freed buffer with t+2 after the read-barrier.
#define KLOOP(NT) do { \
  STAGE(0, 0); \
  STAGE(1, 1); \
  for (int t = 0; t < (NT); ++t) { \
    const int b_ = t & 1; \
    if (t + 1 < (NT)) { VMCNT8; } else { VMCNT0; } \
    BARRIER(); \
    COMPUTE(b_); \
    if (t + 2 < (NT)) { \
      LGKM0; \
      BARRIER(); \
      STAGE(b_, t + 2); \
    } \
  } \
} while (0)

// ---- GEMM1: h = gelu(x[tok] @ up[e]^T) ----
__global__ __launch_bounds__(512, 2) void gemm_up_kernel(
    const unsigned short* __restrict__ xb, const unsigned short* __restrict__ wb,
    const int* __restrict__ counts, const int* __restrict__ offs,
    const int* __restrict__ rowmap, const int* __restrict__ nrt,
    const int* __restrict__ tlist, unsigned short* __restrict__ h) {
  // XCD-group swizzle: 16 same-rt blocks (sharing the A tile) -> one XCD;
  // rt-groups round-robin over XCDs (dead tail stays balanced).
  const int o = blockIdx.x;
  const int xcd = o & 7, mslot = o >> 3;
  const int ct = mslot % 16;
  const int gy = xcd + 8 * (mslot / 16);   // in [0,72)
  if (gy >= nrt[0]) return;
  const int item = rowmap[gy];
  const int e = item >> 16, rt = item & 0xFFFF;
  const int cnt = counts[e];

  __shared__ unsigned short sA[2][BM * BK];
  __shared__ unsigned short sB[2][BN * BK];

  const int tid = threadIdx.x;
  const int wid = tid >> 6, ln = tid & 63;
  const int srow = tid >> 3;
  const int swz  = (tid & 7) ^ (srow & 7);

  const unsigned short* asrc[4];
#pragma unroll
  for (int i = 0; i < 4; ++i) {
    int r = rt * BM + i * 64 + srow;
    int tok = tlist[e * T_TOK + (r < cnt ? r : cnt - 1)];
    asrc[i] = xb + (size_t)tok * DM + swz * 8;
  }
  const unsigned short* bsrc[4];
#pragma unroll
  for (int i = 0; i < 4; ++i)
    bsrc[i] = wb + (size_t)e * DFF * DM + (size_t)(ct * BN + i * 64 + srow) * DM + swz * 8;

  const int wr = (wid >> 2) * 128, wc = (wid & 3) * 64;
  const int lr = ln & 15, g = ln >> 4;

  f32x4 acc[8][4] = {};

  KLOOP(DM / BK);   // 16

  const size_t hbase = (size_t)offs[e];
#pragma unroll
  for (int m = 0; m < 8; ++m) {
    int rloc = wr + m * 16 + g * 4;
#pragma unroll
    for (int j = 0; j < 4; ++j) {
      int row = rt * BM + rloc + j;
      if (row < cnt) {
        unsigned short* hp = h + (hbase + row) * (size_t)DFF + ct * BN + wc + lr;
#pragma unroll
        for (int n = 0; n < 4; ++n) hp[n * 16] = f2bf(gelu_exact(acc[m][n][j]));
      }
    }
  }
}

// ---- GEMM2: out[tok] += w * (h @ down[e]^T) ----
__global__ __launch_bounds__(512, 2) void gemm_down_kernel(
    const unsigned short* __restrict__ h, const unsigned short* __restrict__ wb,
    const int* __restrict__ counts, const int* __restrict__ offs,
    const int* __restrict__ rowmap, const int* __restrict__ nrt,
    const int* __restrict__ tlist, const float* __restrict__ wlist,
    float* __restrict__ out) {
  // XCD-group swizzle: 4 same-rt blocks -> one XCD.
  const int o = blockIdx.x;
  const int xcd = o & 7, mslot = o >> 3;
  const int ct = mslot % 4;
  const int gy = xcd + 8 * (mslot / 4);    // in [0,72)
  if (gy >= nrt[0]) return;
  const int item = rowmap[gy];
  const int e = item >> 16, rt = item & 0xFFFF;
  const int cnt = counts[e];

  __shared__ unsigned short sA[2][BM * BK];
  __shared__ unsigned short sB[2][BN * BK];

  const int tid = threadIdx.x;
  const int wid = tid >> 6, ln = tid & 63;
  const int srow = tid >> 3;
  const int swz  = (tid & 7) ^ (srow & 7);
  const size_t hbase = (size_t)offs[e];

  const unsigned short* asrc[4];
#pragma unroll
  for (int i = 0; i < 4; ++i) {
    int r = rt * BM + i * 64 + srow;
    size_t hrow = hbase + (size_t)(r < cnt ? r : cnt - 1);
    asrc[i] = h + hrow * DFF + swz * 8;
  }
  const unsigned short* bsrc[4];
#pragma unroll
  for (int i = 0; i < 4; ++i)
    bsrc[i] = wb + (size_t)e * DM * DFF + (size_t)(ct * BN + i * 64 + srow) * DFF + swz * 8;

  const int wr = (wid >> 2) * 128, wc = (wid & 3) * 64;
  const int lr = ln & 15, g = ln >> 4;

  f32x4 acc[8][4] = {};

  KLOOP(DFF / BK);  // 64

#pragma unroll
  for (int m = 0; m < 8; ++m) {
    int rloc = wr + m * 16 + g * 4;
#pragma unroll
    for (int j = 0; j < 4; ++j) {
      int row = rt * BM + rloc + j;
      if (row < cnt) {
        int tok = tlist[e * T_TOK + row];
        float w = wlist[e * T_TOK + row];
        float* op = out + (size_t)tok * DM + ct * BN + wc + lr;
#pragma unroll
        for (int n = 0; n < 4; ++n) atomicAdd(op + n * 16, w * acc[m][n][j]);
      }
    }
  }
}

extern "C" void kernel_launch(void* const* d_in, const int* in_sizes, int n_in,
                              void* d_out, int out_size, void* d_ws, size_t ws_size,
                              hipStream_t stream) {
  const float* x  = (const float*)d_in[0];
  const float* rw = (const float*)d_in[1];
  const float* rb = (const float*)d_in[2];
  const float* up = (const float*)d_in[3];
  const float* dn = (const float*)d_in[4];
  float* out = (float*)d_out;
  char* ws = (char*)d_ws;

  int*   counts = (int*)(ws + 0);                          // 8 ints
  int*   offs   = (int*)(ws + 128);                        // 8 ints
  int*   nrt    = (int*)(ws + 256);                        // 1 int
  int*   rowmap = (int*)(ws + 512);                        // 72 ints
  int*   tlist  = (int*)(ws + 1024);                       // 256 KB
  float* wlist  = (float*)(ws + 1024 + 262144);            // 256 KB
  unsigned short* xb = (unsigned short*)(ws + 525312);     // 16 MB  (8192x1024 bf16)
  unsigned short* h  = (unsigned short*)(ws + 17302528);   // 128 MB (16384x4096 bf16)
  unsigned short* wbuf = (unsigned short*)(ws + 151520256);// 64 MB  (8x4096x1024 bf16, reused)

  hipMemsetAsync(counts, 0, 64, stream);
  hipMemsetAsync(d_out, 0, (size_t)T_TOK * DM * sizeof(float), stream);

  cvt_kernel<<<dim3((T_TOK * DM / 8) / 256), 256, 0, stream>>>(x, xb);
  router_kernel<<<dim3(T_TOK / 4), 256, 0, stream>>>(x, rw, rb, counts, tlist, wlist);
  prefix_kernel<<<dim3(1), 1, 0, stream>>>(counts, offs, rowmap, nrt);

  // up weights -> bf16, then GEMM1 (1-D grid, in-kernel XCD-group swizzle)
  cvt_kernel<<<dim3((NE * DFF * DM / 8) / 256), 256, 0, stream>>>(up, wbuf);
  gemm_up_kernel<<<dim3((DFF / BN) * MAXRT), 512, 0, stream>>>(xb, wbuf, counts, offs, rowmap, nrt, tlist, h);

  // down weights -> bf16 (reuse buffer), then GEMM2
  cvt_kernel<<<dim3((NE * DM * DFF / 8) / 256), 256, 0, stream>>>(dn, wbuf);
  gemm_down_kernel<<<dim3((DM / BN) * MAXRT), 512, 0, stream>>>(h, wbuf, counts, offs, rowmap, nrt, tlist, wlist, out);
}